// Round 3
// baseline (308.893 us; speedup 1.0000x reference)
//
#include <hip/hip_runtime.h>

// ---------------- Problem constants ----------------
#define BATCH   2
#define SEQLEN  1024
#define DMODEL  1024
#define DINNER  2048
#define DSTATE  16
#define DCONV   4
#define DTRANK  64
#define GDIM    96              // DTRANK + 2*DSTATE
#define MROWS   (BATCH*SEQLEN)  // 2048

#define NCHUNK  64              // chunks over L
#define LCHUNK  16              // SEQLEN / NCHUNK
#define SPLITX  32              // split-K for x_proj

typedef __attribute__((ext_vector_type(8))) short bf16x8_t;
typedef __attribute__((ext_vector_type(4))) float f32x4_t;
typedef __attribute__((ext_vector_type(4))) unsigned short u16x4_t;
typedef unsigned short ushort_t;

// bf16 <-> f32 helpers (round-to-nearest-even)
__device__ __forceinline__ unsigned short f2bf(float x) {
    union { float f; unsigned int u; } v; v.f = x;
    unsigned int r = v.u + 0x7FFFu + ((v.u >> 16) & 1u);
    return (unsigned short)(r >> 16);
}
__device__ __forceinline__ float bf2f(unsigned short h) {
    union { unsigned int u; float f; } v; v.u = ((unsigned int)h) << 16;
    return v.f;
}

// async global->LDS, 16B per lane; lds base must be wave-uniform (HW writes lane i at base+16i)
__device__ __forceinline__ void gload_lds16(const ushort_t* g, short* l) {
    __builtin_amdgcn_global_load_lds(
        (const __attribute__((address_space(1))) unsigned int*)g,
        (__attribute__((address_space(3))) unsigned int*)l, 16, 0, 0);
}

// ---------------- fused f32->bf16 convert of GEMM operands + zero-fill of atomic sinks ----------
#define N1 (MROWS*DMODEL)        // hidden
#define N2 (2*DINNER*DMODEL)     // in_proj_w
#define N3 (GDIM*DINNER)         // x_proj_w
#define N4 (DINNER*DTRANK)       // dt_proj_w
#define N5 (DMODEL*DINNER)       // out_proj_w
#define NTOT (N1+N2+N3+N4+N5)
#define CVTN (NTOT/4)            // vec4 convert threads
#define Z1   (MROWS*DMODEL/4)    // d_out zero vec4
#define Z2   (MROWS*GDIM/4)      // xdbl zero vec4
#define CVTBLK ((CVTN + Z1 + Z2) / 256)   // exact: 10752
__global__ __launch_bounds__(256)
void cvt5z_kernel(const float* __restrict__ s1, const float* __restrict__ s2,
                  const float* __restrict__ s3, const float* __restrict__ s4,
                  const float* __restrict__ s5,
                  ushort_t* o1, ushort_t* o2, ushort_t* o3, ushort_t* o4, ushort_t* o5,
                  float* __restrict__ z1, float* __restrict__ z2) {
    int t = blockIdx.x * 256 + threadIdx.x;
    if (t < CVTN) {
        int idx = t * 4;
        const float* src; ushort_t* dst;
        if (idx < N1)              { src = s1; dst = o1; }
        else if ((idx -= N1) < N2) { src = s2; dst = o2; }
        else if ((idx -= N2) < N3) { src = s3; dst = o3; }
        else if ((idx -= N3) < N4) { src = s4; dst = o4; }
        else                       { idx -= N4; src = s5; dst = o5; }
        f32x4_t v = *(const f32x4_t*)(src + idx);
        u16x4_t o;
        #pragma unroll
        for (int j = 0; j < 4; j++) o[j] = f2bf(v[j]);
        *(u16x4_t*)(dst + idx) = o;
    } else if ((t -= CVTN) < Z1) {
        ((f32x4_t*)z1)[t] = (f32x4_t){0.f, 0.f, 0.f, 0.f};
    } else {
        t -= Z1;
        ((f32x4_t*)z2)[t] = (f32x4_t){0.f, 0.f, 0.f, 0.f};
    }
}

// ---------------- 128x128 bf16 NT MFMA GEMM: gload_lds + XOR swizzle + 2-phase dbuf ---------
// C[m,n] = sum_k A[m,k]*W[n,k]. A,W bf16 row-major. M%128==0; (K/gridDim.z)%32==0;
// N ragged allowed (B rows clamped; garbage columns masked at write).
// LDS [2 buf][128 rows][32 shorts], linear dest (global_load_lds requirement).
// Bank-conflict fix (rule #21): slot' = slot ^ (row&3) applied on the GLOBAL source
// (kc permuted per lane) and on the fragment ds_read address; LDS stays linear.
// Pipeline (T3 minimal 2-phase): stage(t+1) issued BEFORE ds_read+MFMA of t;
// one __syncthreads (vmcnt(0)+lgkmcnt(0)+barrier) per K-step -> load latency overlaps compute.
// EPI: 1 = bf16 softplus(v + bias[n]) -> out0
//      3 = xz split: col < DINNER -> f32 out0; else f32 out1 (both stride DINNER)
//      4 = atomicAdd f32 into out0[m*N+n]  (split-K accumulate, out0 pre-zeroed)
template<int EPI>
__global__ __launch_bounds__(256)
void gemm_bf(const ushort_t* __restrict__ A, const ushort_t* __restrict__ W,
             void* __restrict__ out0, void* __restrict__ out1,
             const float* __restrict__ bias, int M, int N, int K) {
    __shared__ __align__(16) short As[2][128 * 32];   // 2 x 8 KB
    __shared__ __align__(16) short Bs[2][128 * 32];   // 2 x 8 KB

    const int tid  = threadIdx.x;
    const int m0   = blockIdx.x * 128;
    const int n0   = blockIdx.y * 128;
    const int klen = K / gridDim.z;
    const int kbeg = blockIdx.z * klen;

    const int w    = tid >> 6;          // wave 0..3
    const int lane = tid & 63;
    const int quad = lane >> 4;
    const int l15  = lane & 15;
    const int wm   = (w >> 1) * 64;
    const int wn   = (w & 1) * 64;

    // staging: call (w,q) covers LDS shorts [(2w+q)*512,+512) = rows (2w+q)*16..+15, linear.
    // lane l -> row (2w+q)*16 + (l>>2), LDS slot (l&3). Source slot = (l&3)^(row&3)
    // (inverse swizzle; row&3 == (l>>2)&3), so a read of slot q^(row&3) yields k-chunk q.
    const int rA0 = (w * 2 + 0) * 16 + (lane >> 2);
    const int rA1 = (w * 2 + 1) * 16 + (lane >> 2);
    const int kc  = (((lane & 3) ^ ((lane >> 2) & 3)) << 3);   // swizzled global k-offset (shorts)
    const int arow0 = m0 + rA0;
    const int arow1 = m0 + rA1;
    int brow0 = n0 + rA0; if (brow0 > N - 1) brow0 = N - 1;
    int brow1 = n0 + rA1; if (brow1 > N - 1) brow1 = N - 1;

    f32x4_t acc[4][4];
    #pragma unroll
    for (int i = 0; i < 4; i++)
        #pragma unroll
        for (int j = 0; j < 4; j++)
            acc[i][j] = (f32x4_t){0.f, 0.f, 0.f, 0.f};

    // prologue: stage K-step 0 into buf 0
    {
        const int kk = kbeg + kc;
        gload_lds16(A + (size_t)arow0 * K + kk, &As[0][(w * 2 + 0) * 512]);
        gload_lds16(A + (size_t)arow1 * K + kk, &As[0][(w * 2 + 1) * 512]);
        gload_lds16(W + (size_t)brow0 * K + kk, &Bs[0][(w * 2 + 0) * 512]);
        gload_lds16(W + (size_t)brow1 * K + kk, &Bs[0][(w * 2 + 1) * 512]);
    }
    __syncthreads();

    int cur = 0;
    for (int k0 = 0; k0 < klen; k0 += 32) {
        // issue next tile's loads first (latency hides under ds_read+MFMA below)
        if (k0 + 32 < klen) {
            const int kk = kbeg + k0 + 32 + kc;
            gload_lds16(A + (size_t)arow0 * K + kk, &As[cur ^ 1][(w * 2 + 0) * 512]);
            gload_lds16(A + (size_t)arow1 * K + kk, &As[cur ^ 1][(w * 2 + 1) * 512]);
            gload_lds16(W + (size_t)brow0 * K + kk, &Bs[cur ^ 1][(w * 2 + 0) * 512]);
            gload_lds16(W + (size_t)brow1 * K + kk, &Bs[cur ^ 1][(w * 2 + 1) * 512]);
        }
        bf16x8_t af[4], bfv[4];
        #pragma unroll
        for (int mi = 0; mi < 4; mi++) {
            int row = wm + mi * 16 + l15;
            af[mi] = *(const bf16x8_t*)(&As[cur][row * 32 + ((quad ^ (row & 3)) << 3)]);
        }
        #pragma unroll
        for (int ni = 0; ni < 4; ni++) {
            int row = wn + ni * 16 + l15;
            bfv[ni] = *(const bf16x8_t*)(&Bs[cur][row * 32 + ((quad ^ (row & 3)) << 3)]);
        }
        #pragma unroll
        for (int mi = 0; mi < 4; mi++)
            #pragma unroll
            for (int ni = 0; ni < 4; ni++)
                acc[mi][ni] = __builtin_amdgcn_mfma_f32_16x16x32_bf16(af[mi], bfv[ni], acc[mi][ni], 0, 0, 0);
        __syncthreads();   // drains vmcnt(0) (prefetch, overlapped) + lgkmcnt + barrier
        cur ^= 1;
    }

    #pragma unroll
    for (int mi = 0; mi < 4; mi++) {
        #pragma unroll
        for (int ni = 0; ni < 4; ni++) {
            #pragma unroll
            for (int r = 0; r < 4; r++) {
                int gm = m0 + wm + mi * 16 + quad * 4 + r;
                int gn = n0 + wn + ni * 16 + l15;
                if (gn < N) {
                    float v = acc[mi][ni][r];
                    if (EPI == 1) {
                        float t = v + bias[gn];
                        float sp = (t > 20.f) ? t : log1pf(__expf(t));
                        ((ushort_t*)out0)[(size_t)gm * N + gn] = f2bf(sp);
                    } else if (EPI == 3) {
                        if (gn < DINNER)
                            ((float*)out0)[(size_t)gm * DINNER + gn] = v;
                        else
                            ((float*)out1)[(size_t)gm * DINNER + (gn - DINNER)] = v;
                    } else {   // EPI == 4
                        atomicAdd(&((float*)out0)[(size_t)gm * N + gn], v);
                    }
                }
            }
        }
    }
}

// ---------------- fused: causal conv+silu (blocks [0,CONVBLK)) + text gate ----------------
#define CONVBLK ((MROWS*DINNER)/256)   // 16384
__global__ __launch_bounds__(256)
void convgate_kernel(const float* __restrict__ x,
                     const float* __restrict__ cw,
                     const float* __restrict__ cb,
                     ushort_t* __restrict__ xc,
                     const float* __restrict__ xt,
                     const float* __restrict__ gw,
                     const float* __restrict__ gb,
                     float* __restrict__ gate) {
    if (blockIdx.x < CONVBLK) {
        int idx = blockIdx.x * 256 + threadIdx.x;
        int d  = idx & (DINNER - 1);
        int bl = idx >> 11;
        int l  = bl & (SEQLEN - 1);
        float acc = cb[d];
        #pragma unroll
        for (int j = 0; j < DCONV; j++) {
            int lj = l - (DCONV - 1) + j;
            if (lj >= 0)
                acc += cw[d * DCONV + j] * x[(size_t)(bl - (DCONV - 1) + j) * DINNER + d];
        }
        float v = acc / (1.f + __expf(-acc));   // silu
        xc[idx] = f2bf(v);
    } else {
        int g = blockIdx.x - CONVBLK;
        int b = g / GDIM, j = g % GDIM;
        int tid = threadIdx.x;
        float s = 0.f;
        for (int k = tid; k < DMODEL; k += 256)
            s += xt[b * DMODEL + k] * gw[j * DMODEL + k];
        #pragma unroll
        for (int o = 32; o > 0; o >>= 1) s += __shfl_down(s, o);
        __shared__ float red[4];
        if ((tid & 63) == 0) red[tid >> 6] = s;
        __syncthreads();
        if (tid == 0) {
            float t = red[0] + red[1] + red[2] + red[3] + gb[j];
            gate[b * GDIM + j] = 1.f / (1.f + __expf(-t));
        }
    }
}

// ---------------- gate multiply + split into dt bf16, B, C (x_dbl already reduced) ----------
__global__ void gatemul_kernel(const float* __restrict__ xp,   // [MROWS][GDIM] f32
                               const float* __restrict__ gate,
                               ushort_t* __restrict__ dt,
                               float* __restrict__ Bm,
                               float* __restrict__ Cm) {
    int idx = blockIdx.x * 256 + threadIdx.x;
    if (idx >= MROWS * GDIM) return;
    int j  = idx % GDIM;
    int bl = idx / GDIM;
    int b  = bl >> 10;
    float v = xp[idx] * gate[b * GDIM + j];
    if (j < DTRANK)               dt[bl * DTRANK + j] = f2bf(v);
    else if (j < DTRANK + DSTATE) Bm[bl * DSTATE + (j - DTRANK)] = v;
    else                          Cm[bl * DSTATE + (j - DTRANK - DSTATE)] = v;
}

// ---------------- scan pass 1: per-chunk local h and sum(delta) ----------------
// hfin layout: [b][d][c][n] (64B contiguous); dsum layout: [b][c][d] (coalesced write).
// Chunk dA-product p[n] = exp(Ac[n] * sum_s dv_s) -- store only the scalar sum.
__global__ __launch_bounds__(256)
void scan1_kernel(const ushort_t* __restrict__ delta,
                  const ushort_t* __restrict__ xc,
                  const float* __restrict__ Bm,
                  const float* __restrict__ A_log,
                  float* __restrict__ hfin,
                  float* __restrict__ dsum) {
    __shared__ float sBm[LCHUNK][DSTATE];
    int tid = threadIdx.x;
    int d = blockIdx.x * 256 + tid;
    int b = blockIdx.y;
    int c = blockIdx.z;
    int l0 = c * LCHUNK;
    for (int t = tid; t < LCHUNK * DSTATE; t += 256)
        sBm[t >> 4][t & 15] = Bm[((size_t)(b * SEQLEN + l0 + (t >> 4))) * DSTATE + (t & 15)];
    __syncthreads();

    float Ac[DSTATE];
    #pragma unroll
    for (int n = 0; n < DSTATE; n++)
        Ac[n] = -__expf(A_log[d * DSTATE + n]);
    float h[DSTATE];
    #pragma unroll
    for (int n = 0; n < DSTATE; n++) h[n] = 0.f;
    float ds = 0.f;

    for (int s = 0; s < LCHUNK; s++) {
        size_t ix = (size_t)(b * SEQLEN + l0 + s) * DINNER + d;
        float dv = bf2f(delta[ix]);
        float xv = bf2f(xc[ix]);
        float dx = dv * xv;
        ds += dv;
        #pragma unroll
        for (int n = 0; n < DSTATE; n++) {
            float e = __expf(dv * Ac[n]);
            h[n] = h[n] * e + dx * sBm[s][n];
        }
    }
    size_t base = ((size_t)(b * DINNER + d) * NCHUNK + c) * DSTATE;
    #pragma unroll
    for (int n = 0; n < DSTATE; n++) hfin[base + n] = h[n];
    dsum[((size_t)b * NCHUNK + c) * DINNER + d] = ds;
}

// ---------------- scan pass 2: block-parallel exclusive scan over chunks, in place ---------
// One block per (b,d): p[c][n] reconstructed as exp(Ac[n]*dsum[c]); Hillis-Steele over c.
// Overwrites hfin with the EXCLUSIVE prefix (state entering chunk c).
__global__ __launch_bounds__(256)
void scan2_kernel(float* __restrict__ hfin,
                  const float* __restrict__ dsum,
                  const float* __restrict__ A_log) {
    __shared__ float sh[NCHUNK * DSTATE];   // 4 KB
    __shared__ float sp[NCHUNK * DSTATE];   // 4 KB
    __shared__ float sAc[DSTATE];
    __shared__ float sds[NCHUNK];
    const int tid = threadIdx.x;
    const int bd  = blockIdx.x;            // b*DINNER + d
    const int b   = bd >> 11;
    const int d   = bd & (DINNER - 1);
    if (tid < DSTATE) sAc[tid] = -__expf(A_log[d * DSTATE + tid]);
    if (tid < NCHUNK) sds[tid] = dsum[((size_t)b * NCHUNK + tid) * DINNER + d];
    const size_t base = (size_t)bd * (NCHUNK * DSTATE);
    float hl[4];
    #pragma unroll
    for (int r = 0; r < 4; r++) hl[r] = hfin[base + tid + r * 256];
    __syncthreads();
    #pragma unroll
    for (int r = 0; r < 4; r++) {
        int i = tid + r * 256;              // i = c*16 + n
        sh[i] = hl[r];
        sp[i] = __expf(sAc[i & 15] * sds[i >> 4]);
    }
    __syncthreads();
    #pragma unroll
    for (int s = 1; s < NCHUNK; s <<= 1) {
        float nh[4], np[4];
        #pragma unroll
        for (int r = 0; r < 4; r++) {
            int i = tid + r * 256;
            int c = i >> 4;
            if (c >= s) {
                int j = i - (s << 4);
                nh[r] = sh[i] + sp[i] * sh[j];
                np[r] = sp[i] * sp[j];
            } else { nh[r] = sh[i]; np[r] = sp[i]; }
        }
        __syncthreads();
        #pragma unroll
        for (int r = 0; r < 4; r++) { int i = tid + r * 256; sh[i] = nh[r]; sp[i] = np[r]; }
        __syncthreads();
    }
    // exclusive: out[c] = inclusive[c-1]; out[0] = 0
    #pragma unroll
    for (int r = 0; r < 4; r++) {
        int i = tid + r * 256;
        hfin[base + i] = (i >> 4) ? sh[i - 16] : 0.f;
    }
}

// ---------------- scan pass 3: load prefix + replay, emit y bf16 in place over xc ----------
__global__ __launch_bounds__(256)
void scan3_kernel(const ushort_t* __restrict__ delta,
                  ushort_t* __restrict__ xc,     // in: xc, out: y
                  const float* __restrict__ z,
                  const float* __restrict__ Bm,
                  const float* __restrict__ Cm,
                  const float* __restrict__ A_log,
                  const float* __restrict__ Dp,
                  const float* __restrict__ h0) {  // exclusive prefixes from scan2
    __shared__ float sBm[LCHUNK][DSTATE];
    __shared__ float sCm[LCHUNK][DSTATE];
    int tid = threadIdx.x;
    int d = blockIdx.x * 256 + tid;
    int b = blockIdx.y;
    int c = blockIdx.z;
    int l0 = c * LCHUNK;
    for (int t = tid; t < LCHUNK * DSTATE; t += 256) {
        size_t src = ((size_t)(b * SEQLEN + l0 + (t >> 4))) * DSTATE + (t & 15);
        sBm[t >> 4][t & 15] = Bm[src];
        sCm[t >> 4][t & 15] = Cm[src];
    }
    __syncthreads();

    float Ac[DSTATE];
    #pragma unroll
    for (int n = 0; n < DSTATE; n++)
        Ac[n] = -__expf(A_log[d * DSTATE + n]);

    float h[DSTATE];
    size_t hb0 = ((size_t)(b * DINNER + d) * NCHUNK + c) * DSTATE;
    #pragma unroll
    for (int n = 0; n < DSTATE; n++) h[n] = h0[hb0 + n];

    float Dv = Dp[d];

    for (int s = 0; s < LCHUNK; s++) {
        size_t ix = (size_t)(b * SEQLEN + l0 + s) * DINNER + d;
        float dv = bf2f(delta[ix]);
        float xv = bf2f(xc[ix]);
        float dx = dv * xv;
        float y = 0.f;
        #pragma unroll
        for (int n = 0; n < DSTATE; n++) {
            float e = __expf(dv * Ac[n]);
            h[n] = h[n] * e + dx * sBm[s][n];
            y += h[n] * sCm[s][n];
        }
        float zv = z[ix];
        float o = (y + Dv * xv) * (zv / (1.f + __expf(-zv)));
        xc[ix] = f2bf(o);                // same thread read-then-write: safe in place
    }
}

// ---------------- launch ----------------
extern "C" void kernel_launch(void* const* d_in, const int* in_sizes, int n_in,
                              void* d_out, int out_size, void* d_ws, size_t ws_size,
                              hipStream_t stream) {
    const float* hidden   = (const float*)d_in[0];
    const float* x_text   = (const float*)d_in[1];
    const float* in_proj  = (const float*)d_in[2];
    const float* conv_w   = (const float*)d_in[3];
    const float* conv_b   = (const float*)d_in[4];
    const float* x_proj   = (const float*)d_in[5];
    const float* dt_proj  = (const float*)d_in[6];
    const float* dt_bias  = (const float*)d_in[7];
    const float* A_log    = (const float*)d_in[8];
    const float* Dparam   = (const float*)d_in[9];
    const float* out_proj = (const float*)d_in[10];
    const float* gate_w   = (const float*)d_in[11];
    const float* gate_b   = (const float*)d_in[12];

    char* ws = (char*)d_ws;
    size_t off = 0;
    auto alloc = [&](size_t bytes) -> char* {
        char* p = ws + off;
        off += (bytes + 255) & ~(size_t)255;
        return p;
    };
    // ~70 MB total.
    ushort_t* hb    = (ushort_t*)alloc((size_t)N1 * 2);   // 4.19 MB
    ushort_t* w_in  = (ushort_t*)alloc((size_t)N2 * 2);   // 8.39 MB -> xc/y after in_proj
    ushort_t* w_x   = (ushort_t*)alloc((size_t)N3 * 2);
    ushort_t* w_dt  = (ushort_t*)alloc((size_t)N4 * 2);
    ushort_t* w_o   = (ushort_t*)alloc((size_t)N5 * 2);   // 4.19 MB
    float*    X     = (float*)alloc((size_t)MROWS * DINNER * 4);  // 16.78 MB
    float*    zbuf  = (float*)alloc((size_t)MROWS * DINNER * 4);  // 16.78 MB
    float*    hfin  = (float*)alloc((size_t)BATCH * DINNER * NCHUNK * DSTATE * 4);  // 16.78 MB
    float*    dsum  = (float*)alloc((size_t)BATCH * NCHUNK * DINNER * 4);           // 1.05 MB
    float*    xdbl  = (float*)alloc((size_t)MROWS * GDIM * 4);                      // 0.79 MB
    float*    gate  = (float*)alloc((size_t)BATCH * GDIM * 4);
    float*    Bm    = (float*)alloc((size_t)MROWS * DSTATE * 4);
    float*    Cm    = (float*)alloc((size_t)MROWS * DSTATE * 4);
    ushort_t* dt    = (ushort_t*)alloc((size_t)MROWS * DTRANK * 2);

    // aliases (lifetimes disjoint, stream-ordered):
    ushort_t* xc    = w_in;            // xc/y bf16, live after in_proj consumed w_in
    ushort_t* delta = (ushort_t*)X;    // 8.39 MB bf16, live [dt_proj..scan3]; X dead after conv

    // 1. convert GEMM operands to bf16 + zero d_out and xdbl (atomic sinks)
    cvt5z_kernel<<<CVTBLK, 256, 0, stream>>>(
        hidden, in_proj, x_proj, dt_proj, out_proj, hb, w_in, w_x, w_dt, w_o,
        (float*)d_out, xdbl);

    // 2. in_proj: xz = hidden @ in_proj^T  (2048 x 4096, K=1024) -> x f32 (X) / z f32
    gemm_bf<3><<<dim3(MROWS / 128, (2 * DINNER) / 128, 1), 256, 0, stream>>>(
        hb, w_in, X, zbuf, nullptr, MROWS, 2 * DINNER, DMODEL);

    // 3. conv+silu -> xc bf16 (over dead w_in)  ++  text gate (fused)
    convgate_kernel<<<CONVBLK + BATCH * GDIM, 256, 0, stream>>>(
        X, conv_w, conv_b, xc, x_text, gate_w, gate_b, gate);

    // 4. x_proj: x_dbl = xc @ x_proj^T (2048 x 96, K=2048), split-K=32, atomicAdd -> xdbl
    gemm_bf<4><<<dim3(MROWS / 128, 1, SPLITX), 256, 0, stream>>>(
        xc, w_x, xdbl, nullptr, nullptr, MROWS, GDIM, DINNER);

    // 5. gate multiply + split -> dt bf16, Bm, Cm
    gatemul_kernel<<<(MROWS * GDIM + 255) / 256, 256, 0, stream>>>(
        xdbl, gate, dt, Bm, Cm);

    // 6. dt_proj + softplus: delta bf16 (2048 x 2048, K=64) -> X
    gemm_bf<1><<<dim3(MROWS / 128, DINNER / 128, 1), 256, 0, stream>>>(
        dt, w_dt, delta, nullptr, dt_bias, MROWS, DINNER, DTRANK);

    // 7. chunked parallel scan, pass 1: per-chunk local h + sum(delta)
    scan1_kernel<<<dim3(DINNER / 256, BATCH, NCHUNK), 256, 0, stream>>>(
        delta, xc, Bm, A_log, hfin, dsum);

    // 7b. pass 2: exclusive chunk-prefix scan (p rebuilt from dsum), in place over hfin
    scan2_kernel<<<BATCH * DINNER, 256, 0, stream>>>(hfin, dsum, A_log);

    // 8. pass 3: load prefix + replay, y bf16 in place over xc
    scan3_kernel<<<dim3(DINNER / 256, BATCH, NCHUNK), 256, 0, stream>>>(
        delta, xc, zbuf, Bm, Cm, A_log, Dparam, hfin);

    // 9. out_proj (2048 x 1024, K=2048), split-K=4, atomicAdd -> d_out (pre-zeroed)
    gemm_bf<4><<<dim3(MROWS / 128, DMODEL / 128, 4), 256, 0, stream>>>(
        xc, w_o, (float*)d_out, nullptr, nullptr, MROWS, DMODEL, DINNER);
}

// Round 4
// 288.205 us; speedup vs baseline: 1.0718x; 1.0718x over previous
//
#include <hip/hip_runtime.h>

// ---------------- Problem constants ----------------
#define BATCH   2
#define SEQLEN  1024
#define DMODEL  1024
#define DINNER  2048
#define DSTATE  16
#define DCONV   4
#define DTRANK  64
#define GDIM    96              // DTRANK + 2*DSTATE
#define MROWS   (BATCH*SEQLEN)  // 2048

#define NCHUNK  64              // chunks over L
#define LCHUNK  16              // SEQLEN / NCHUNK
#define SPLITX  32              // split-K for x_proj

typedef __attribute__((ext_vector_type(8))) short bf16x8_t;
typedef __attribute__((ext_vector_type(4))) float f32x4_t;
typedef __attribute__((ext_vector_type(4))) unsigned short u16x4_t;
typedef unsigned short ushort_t;

// bf16 <-> f32 helpers (round-to-nearest-even)
__device__ __forceinline__ unsigned short f2bf(float x) {
    union { float f; unsigned int u; } v; v.f = x;
    unsigned int r = v.u + 0x7FFFu + ((v.u >> 16) & 1u);
    return (unsigned short)(r >> 16);
}
__device__ __forceinline__ float bf2f(unsigned short h) {
    union { unsigned int u; float f; } v; v.u = ((unsigned int)h) << 16;
    return v.f;
}

// async global->LDS, 16B per lane; lds base must be wave-uniform (HW writes lane i at base+16i)
__device__ __forceinline__ void gload_lds16(const ushort_t* g, short* l) {
    __builtin_amdgcn_global_load_lds(
        (const __attribute__((address_space(1))) unsigned int*)g,
        (__attribute__((address_space(3))) unsigned int*)l, 16, 0, 0);
}

// ---------------- fused f32 -> bf16 convert of all GEMM operands (x4 vectorized) ----------------
#define N1 (MROWS*DMODEL)        // hidden
#define N2 (2*DINNER*DMODEL)     // in_proj_w
#define N3 (GDIM*DINNER)         // x_proj_w
#define N4 (DINNER*DTRANK)       // dt_proj_w
#define N5 (DMODEL*DINNER)       // out_proj_w
#define NTOT (N1+N2+N3+N4+N5)
__global__ __launch_bounds__(256)
void cvt5_kernel(const float* __restrict__ s1, const float* __restrict__ s2,
                 const float* __restrict__ s3, const float* __restrict__ s4,
                 const float* __restrict__ s5,
                 ushort_t* o1, ushort_t* o2, ushort_t* o3, ushort_t* o4, ushort_t* o5) {
    int idx = (blockIdx.x * 256 + threadIdx.x) * 4;
    if (idx >= NTOT) return;
    const float* src; ushort_t* dst;
    if (idx < N1)              { src = s1; dst = o1; }
    else if ((idx -= N1) < N2) { src = s2; dst = o2; }
    else if ((idx -= N2) < N3) { src = s3; dst = o3; }
    else if ((idx -= N3) < N4) { src = s4; dst = o4; }
    else                       { idx -= N4; src = s5; dst = o5; }
    f32x4_t v = *(const f32x4_t*)(src + idx);
    u16x4_t o;
    #pragma unroll
    for (int j = 0; j < 4; j++) o[j] = f2bf(v[j]);
    *(u16x4_t*)(dst + idx) = o;
}

// ---------------- 128x128 bf16 NT MFMA GEMM: gload_lds + bijective XOR swizzle + 2-phase dbuf ----
// C[m,n] = sum_k A[m,k]*W[n,k]. A,W bf16 row-major. M%128==0; (K/gridDim.z)%32==0;
// N ragged allowed (B rows clamped; garbage columns masked at write).
// LDS [2 buf][128 rows][32 shorts], linear dest (global_load_lds requirement).
// Swizzle (rule #21, BOTH sides): LDS slot s (16B units within a row's 64B) of row r holds
// k-chunk s ^ ((r>>1)&3). Source side: staging lane l (row r=l>>2, slot l&3) pre-permutes its
// global k-offset to (l&3)^((l>>3)&3). Read side: chunk q of row r is at slot q^((r>>1)&3).
// Fragment-read bank check (quad=q, rows r..r+15): 128B-position (r&1)*4 + (q^((r>>1)&3))
// is bijective over r&7 -> 8 distinct 16B slots x 2 lanes = 2-way = free (m136).
// Pipeline (T3 minimal 2-phase): stage(t+1) issued BEFORE ds_read+MFMA of t;
// one __syncthreads (vmcnt(0)+lgkmcnt(0)+barrier) per K-step.
// EPI: 0 = f32 partial -> out0 + blockIdx.z*M*N  (split-K)
//      1 = bf16 softplus(v + bias[n]) -> out0
//      3 = xz split: col < DINNER -> f32 out0; else f32 out1 (both stride DINNER)
template<int EPI>
__global__ __launch_bounds__(256)
void gemm_bf(const ushort_t* __restrict__ A, const ushort_t* __restrict__ W,
             void* __restrict__ out0, void* __restrict__ out1,
             const float* __restrict__ bias, int M, int N, int K) {
    __shared__ __align__(16) short As[2][128 * 32];   // 2 x 8 KB
    __shared__ __align__(16) short Bs[2][128 * 32];   // 2 x 8 KB

    const int tid  = threadIdx.x;
    const int m0   = blockIdx.x * 128;
    const int n0   = blockIdx.y * 128;
    const int klen = K / gridDim.z;
    const int kbeg = blockIdx.z * klen;

    const int w    = tid >> 6;          // wave 0..3
    const int lane = tid & 63;
    const int quad = lane >> 4;
    const int l15  = lane & 15;
    const int wm   = (w >> 1) * 64;
    const int wn   = (w & 1) * 64;

    // staging: call (w,q) covers LDS rows (2w+q)*16..+15 linearly; lane l -> row +(l>>2), slot l&3.
    const int rA0 = (w * 2 + 0) * 16 + (lane >> 2);
    const int rA1 = (w * 2 + 1) * 16 + (lane >> 2);
    const int kc  = (((lane & 3) ^ ((lane >> 3) & 3)) << 3);   // pre-swizzled global k-offset (shorts)
    const int arow0 = m0 + rA0;
    const int arow1 = m0 + rA1;
    int brow0 = n0 + rA0; if (brow0 > N - 1) brow0 = N - 1;
    int brow1 = n0 + rA1; if (brow1 > N - 1) brow1 = N - 1;

    // fragment-read swizzled slot offset (shorts); loop-invariant
    const int sw = ((quad ^ ((l15 >> 1) & 3)) << 3);

    f32x4_t acc[4][4];
    #pragma unroll
    for (int i = 0; i < 4; i++)
        #pragma unroll
        for (int j = 0; j < 4; j++)
            acc[i][j] = (f32x4_t){0.f, 0.f, 0.f, 0.f};

    // prologue: stage K-step 0 into buf 0
    {
        const int kk = kbeg + kc;
        gload_lds16(A + (size_t)arow0 * K + kk, &As[0][(w * 2 + 0) * 512]);
        gload_lds16(A + (size_t)arow1 * K + kk, &As[0][(w * 2 + 1) * 512]);
        gload_lds16(W + (size_t)brow0 * K + kk, &Bs[0][(w * 2 + 0) * 512]);
        gload_lds16(W + (size_t)brow1 * K + kk, &Bs[0][(w * 2 + 1) * 512]);
    }
    __syncthreads();

    int cur = 0;
    for (int k0 = 0; k0 < klen; k0 += 32) {
        // issue next tile's loads first (latency hides under ds_read+MFMA below)
        if (k0 + 32 < klen) {
            const int kk = kbeg + k0 + 32 + kc;
            gload_lds16(A + (size_t)arow0 * K + kk, &As[cur ^ 1][(w * 2 + 0) * 512]);
            gload_lds16(A + (size_t)arow1 * K + kk, &As[cur ^ 1][(w * 2 + 1) * 512]);
            gload_lds16(W + (size_t)brow0 * K + kk, &Bs[cur ^ 1][(w * 2 + 0) * 512]);
            gload_lds16(W + (size_t)brow1 * K + kk, &Bs[cur ^ 1][(w * 2 + 1) * 512]);
        }
        bf16x8_t af[4], bfv[4];
        #pragma unroll
        for (int mi = 0; mi < 4; mi++)
            af[mi] = *(const bf16x8_t*)(&As[cur][(wm + mi * 16 + l15) * 32 + sw]);
        #pragma unroll
        for (int ni = 0; ni < 4; ni++)
            bfv[ni] = *(const bf16x8_t*)(&Bs[cur][(wn + ni * 16 + l15) * 32 + sw]);
        #pragma unroll
        for (int mi = 0; mi < 4; mi++)
            #pragma unroll
            for (int ni = 0; ni < 4; ni++)
                acc[mi][ni] = __builtin_amdgcn_mfma_f32_16x16x32_bf16(af[mi], bfv[ni], acc[mi][ni], 0, 0, 0);
        __syncthreads();   // drains vmcnt (prefetch, overlapped) + lgkmcnt + barrier
        cur ^= 1;
    }

    const size_t zoff = (size_t)blockIdx.z * M * N;
    #pragma unroll
    for (int mi = 0; mi < 4; mi++) {
        #pragma unroll
        for (int ni = 0; ni < 4; ni++) {
            #pragma unroll
            for (int r = 0; r < 4; r++) {
                int gm = m0 + wm + mi * 16 + quad * 4 + r;
                int gn = n0 + wn + ni * 16 + l15;
                if (gn < N) {
                    float v = acc[mi][ni][r];
                    if (EPI == 0) {
                        ((float*)out0)[zoff + (size_t)gm * N + gn] = v;
                    } else if (EPI == 1) {
                        float t = v + bias[gn];
                        float sp = (t > 20.f) ? t : log1pf(__expf(t));
                        ((ushort_t*)out0)[(size_t)gm * N + gn] = f2bf(sp);
                    } else {
                        if (gn < DINNER)
                            ((float*)out0)[(size_t)gm * DINNER + gn] = v;
                        else
                            ((float*)out1)[(size_t)gm * DINNER + (gn - DINNER)] = v;
                    }
                }
            }
        }
    }
}

// ---------------- fused: causal conv+silu (blocks [0,CONVBLK)) + text gate ----------------
#define CONVBLK ((MROWS*DINNER)/256)   // 16384
__global__ __launch_bounds__(256)
void convgate_kernel(const float* __restrict__ x,
                     const float* __restrict__ cw,
                     const float* __restrict__ cb,
                     ushort_t* __restrict__ xc,
                     const float* __restrict__ xt,
                     const float* __restrict__ gw,
                     const float* __restrict__ gb,
                     float* __restrict__ gate) {
    if (blockIdx.x < CONVBLK) {
        int idx = blockIdx.x * 256 + threadIdx.x;
        int d  = idx & (DINNER - 1);
        int bl = idx >> 11;
        int l  = bl & (SEQLEN - 1);
        float acc = cb[d];
        #pragma unroll
        for (int j = 0; j < DCONV; j++) {
            int lj = l - (DCONV - 1) + j;
            if (lj >= 0)
                acc += cw[d * DCONV + j] * x[(size_t)(bl - (DCONV - 1) + j) * DINNER + d];
        }
        float v = acc / (1.f + __expf(-acc));   // silu
        xc[idx] = f2bf(v);
    } else {
        int g = blockIdx.x - CONVBLK;
        int b = g / GDIM, j = g % GDIM;
        int tid = threadIdx.x;
        float s = 0.f;
        for (int k = tid; k < DMODEL; k += 256)
            s += xt[b * DMODEL + k] * gw[j * DMODEL + k];
        #pragma unroll
        for (int o = 32; o > 0; o >>= 1) s += __shfl_down(s, o);
        __shared__ float red[4];
        if ((tid & 63) == 0) red[tid >> 6] = s;
        __syncthreads();
        if (tid == 0) {
            float t = red[0] + red[1] + red[2] + red[3] + gb[j];
            gate[b * GDIM + j] = 1.f / (1.f + __expf(-t));
        }
    }
}

// ---------------- reduce SPLITX split-K partials + gate; split into dt bf16, B, C ----------------
__global__ void gatemul_kernel(const float* __restrict__ xp,   // [SPLITX][MROWS][GDIM]
                               const float* __restrict__ gate,
                               ushort_t* __restrict__ dt,
                               float* __restrict__ Bm,
                               float* __restrict__ Cm) {
    int idx = blockIdx.x * 256 + threadIdx.x;
    if (idx >= MROWS * GDIM) return;
    int j  = idx % GDIM;
    int bl = idx / GDIM;
    int b  = bl >> 10;
    float v = 0.f;
    #pragma unroll
    for (int z = 0; z < SPLITX; z++)
        v += xp[(size_t)z * MROWS * GDIM + idx];
    v *= gate[b * GDIM + j];
    if (j < DTRANK)               dt[bl * DTRANK + j] = f2bf(v);
    else if (j < DTRANK + DSTATE) Bm[bl * DSTATE + (j - DTRANK)] = v;
    else                          Cm[bl * DSTATE + (j - DTRANK - DSTATE)] = v;
}

// ---------------- scan pass 1: per-chunk local h and sum(delta) ----------------
// hfin layout: [b][d][c][n] (64B contiguous); dsum layout: [b][c][d] (coalesced write).
// Chunk dA-product p[n] = exp(Ac[n] * sum_s dv_s) -- store only the scalar sum.
__global__ __launch_bounds__(256)
void scan1_kernel(const ushort_t* __restrict__ delta,
                  const ushort_t* __restrict__ xc,
                  const float* __restrict__ Bm,
                  const float* __restrict__ A_log,
                  float* __restrict__ hfin,
                  float* __restrict__ dsum) {
    __shared__ float sBm[LCHUNK][DSTATE];
    int tid = threadIdx.x;
    int d = blockIdx.x * 256 + tid;
    int b = blockIdx.y;
    int c = blockIdx.z;
    int l0 = c * LCHUNK;
    for (int t = tid; t < LCHUNK * DSTATE; t += 256)
        sBm[t >> 4][t & 15] = Bm[((size_t)(b * SEQLEN + l0 + (t >> 4))) * DSTATE + (t & 15)];
    __syncthreads();

    float Ac[DSTATE];
    #pragma unroll
    for (int n = 0; n < DSTATE; n++)
        Ac[n] = -__expf(A_log[d * DSTATE + n]);
    float h[DSTATE];
    #pragma unroll
    for (int n = 0; n < DSTATE; n++) h[n] = 0.f;
    float ds = 0.f;

    for (int s = 0; s < LCHUNK; s++) {
        size_t ix = (size_t)(b * SEQLEN + l0 + s) * DINNER + d;
        float dv = bf2f(delta[ix]);
        float xv = bf2f(xc[ix]);
        float dx = dv * xv;
        ds += dv;
        #pragma unroll
        for (int n = 0; n < DSTATE; n++) {
            float e = __expf(dv * Ac[n]);
            h[n] = h[n] * e + dx * sBm[s][n];
        }
    }
    size_t base = ((size_t)(b * DINNER + d) * NCHUNK + c) * DSTATE;
    #pragma unroll
    for (int n = 0; n < DSTATE; n++) hfin[base + n] = h[n];
    dsum[((size_t)b * NCHUNK + c) * DINNER + d] = ds;
}

// ---------------- scan pass 2: block-parallel exclusive scan over chunks, in place ---------
// One block per (b,d): p[c][n] reconstructed as exp(Ac[n]*dsum[c]); Hillis-Steele over c.
// Overwrites hfin with the EXCLUSIVE prefix (state entering chunk c).
__global__ __launch_bounds__(256)
void scan2_kernel(float* __restrict__ hfin,
                  const float* __restrict__ dsum,
                  const float* __restrict__ A_log) {
    __shared__ float sh[NCHUNK * DSTATE];   // 4 KB
    __shared__ float sp[NCHUNK * DSTATE];   // 4 KB
    __shared__ float sAc[DSTATE];
    __shared__ float sds[NCHUNK];
    const int tid = threadIdx.x;
    const int bd  = blockIdx.x;            // b*DINNER + d
    const int b   = bd >> 11;
    const int d   = bd & (DINNER - 1);
    if (tid < DSTATE) sAc[tid] = -__expf(A_log[d * DSTATE + tid]);
    if (tid < NCHUNK) sds[tid] = dsum[((size_t)b * NCHUNK + tid) * DINNER + d];
    const size_t base = (size_t)bd * (NCHUNK * DSTATE);
    float hl[4];
    #pragma unroll
    for (int r = 0; r < 4; r++) hl[r] = hfin[base + tid + r * 256];
    __syncthreads();
    #pragma unroll
    for (int r = 0; r < 4; r++) {
        int i = tid + r * 256;              // i = c*16 + n
        sh[i] = hl[r];
        sp[i] = __expf(sAc[i & 15] * sds[i >> 4]);
    }
    __syncthreads();
    #pragma unroll
    for (int s = 1; s < NCHUNK; s <<= 1) {
        float nh[4], np[4];
        #pragma unroll
        for (int r = 0; r < 4; r++) {
            int i = tid + r * 256;
            int c = i >> 4;
            if (c >= s) {
                int j = i - (s << 4);
                nh[r] = sh[i] + sp[i] * sh[j];
                np[r] = sp[i] * sp[j];
            } else { nh[r] = sh[i]; np[r] = sp[i]; }
        }
        __syncthreads();
        #pragma unroll
        for (int r = 0; r < 4; r++) { int i = tid + r * 256; sh[i] = nh[r]; sp[i] = np[r]; }
        __syncthreads();
    }
    // exclusive: out[c] = inclusive[c-1]; out[0] = 0
    #pragma unroll
    for (int r = 0; r < 4; r++) {
        int i = tid + r * 256;
        hfin[base + i] = (i >> 4) ? sh[i - 16] : 0.f;
    }
}

// ---------------- scan pass 3: load prefix + replay, emit y bf16 in place over xc ----------
__global__ __launch_bounds__(256)
void scan3_kernel(const ushort_t* __restrict__ delta,
                  ushort_t* __restrict__ xc,     // in: xc, out: y
                  const float* __restrict__ z,
                  const float* __restrict__ Bm,
                  const float* __restrict__ Cm,
                  const float* __restrict__ A_log,
                  const float* __restrict__ Dp,
                  const float* __restrict__ h0) {  // exclusive prefixes from scan2
    __shared__ float sBm[LCHUNK][DSTATE];
    __shared__ float sCm[LCHUNK][DSTATE];
    int tid = threadIdx.x;
    int d = blockIdx.x * 256 + tid;
    int b = blockIdx.y;
    int c = blockIdx.z;
    int l0 = c * LCHUNK;
    for (int t = tid; t < LCHUNK * DSTATE; t += 256) {
        size_t src = ((size_t)(b * SEQLEN + l0 + (t >> 4))) * DSTATE + (t & 15);
        sBm[t >> 4][t & 15] = Bm[src];
        sCm[t >> 4][t & 15] = Cm[src];
    }
    __syncthreads();

    float Ac[DSTATE];
    #pragma unroll
    for (int n = 0; n < DSTATE; n++)
        Ac[n] = -__expf(A_log[d * DSTATE + n]);

    float h[DSTATE];
    size_t hb0 = ((size_t)(b * DINNER + d) * NCHUNK + c) * DSTATE;
    #pragma unroll
    for (int n = 0; n < DSTATE; n++) h[n] = h0[hb0 + n];

    float Dv = Dp[d];

    for (int s = 0; s < LCHUNK; s++) {
        size_t ix = (size_t)(b * SEQLEN + l0 + s) * DINNER + d;
        float dv = bf2f(delta[ix]);
        float xv = bf2f(xc[ix]);
        float dx = dv * xv;
        float y = 0.f;
        #pragma unroll
        for (int n = 0; n < DSTATE; n++) {
            float e = __expf(dv * Ac[n]);
            h[n] = h[n] * e + dx * sBm[s][n];
            y += h[n] * sCm[s][n];
        }
        float zv = z[ix];
        float o = (y + Dv * xv) * (zv / (1.f + __expf(-zv)));
        xc[ix] = f2bf(o);                // same thread read-then-write: safe in place
    }
}

// ---------------- out_proj split-K=4 reduce ----------------
__global__ void reduce4_kernel(const float* __restrict__ p, float* __restrict__ out, int n) {
    int i = blockIdx.x * 256 + threadIdx.x;
    if (i < n)
        out[i] = (p[i] + p[(size_t)n + i]) + (p[2 * (size_t)n + i] + p[3 * (size_t)n + i]);
}

// ---------------- launch ----------------
extern "C" void kernel_launch(void* const* d_in, const int* in_sizes, int n_in,
                              void* d_out, int out_size, void* d_ws, size_t ws_size,
                              hipStream_t stream) {
    const float* hidden   = (const float*)d_in[0];
    const float* x_text   = (const float*)d_in[1];
    const float* in_proj  = (const float*)d_in[2];
    const float* conv_w   = (const float*)d_in[3];
    const float* conv_b   = (const float*)d_in[4];
    const float* x_proj   = (const float*)d_in[5];
    const float* dt_proj  = (const float*)d_in[6];
    const float* dt_bias  = (const float*)d_in[7];
    const float* A_log    = (const float*)d_in[8];
    const float* Dparam   = (const float*)d_in[9];
    const float* out_proj = (const float*)d_in[10];
    const float* gate_w   = (const float*)d_in[11];
    const float* gate_b   = (const float*)d_in[12];

    char* ws = (char*)d_ws;
    size_t off = 0;
    auto alloc = [&](size_t bytes) -> char* {
        char* p = ws + off;
        off += (bytes + 255) & ~(size_t)255;
        return p;
    };
    // ~78 MB total. X and zbuf MUST be adjacent (out_proj partials span both).
    ushort_t* hb    = (ushort_t*)alloc((size_t)N1 * 2);   // 4.19 MB
    ushort_t* w_in  = (ushort_t*)alloc((size_t)N2 * 2);   // 8.39 MB -> xc/y after in_proj
    ushort_t* w_x   = (ushort_t*)alloc((size_t)N3 * 2);
    ushort_t* w_dt  = (ushort_t*)alloc((size_t)N4 * 2);
    ushort_t* w_o   = (ushort_t*)alloc((size_t)N5 * 2);   // 4.19 MB
    float*    X     = (float*)alloc((size_t)MROWS * DINNER * 4);  // 16.78 MB
    float*    zbuf  = (float*)alloc((size_t)MROWS * DINNER * 4);  // 16.78 MB, adjacent to X
    float*    xpart = (float*)alloc((size_t)SPLITX * MROWS * GDIM * 4);  // 25.17 MB
    float*    dsum  = (float*)alloc((size_t)BATCH * NCHUNK * DINNER * 4);  // 1.05 MB
    float*    gate  = (float*)alloc((size_t)BATCH * GDIM * 4);
    float*    Bm    = (float*)alloc((size_t)MROWS * DSTATE * 4);
    float*    Cm    = (float*)alloc((size_t)MROWS * DSTATE * 4);
    ushort_t* dt    = (ushort_t*)alloc((size_t)MROWS * DTRANK * 2);

    // aliases (lifetimes disjoint, stream-ordered):
    ushort_t* xc    = w_in;            // xc/y bf16, live after in_proj consumed w_in
    ushort_t* delta = (ushort_t*)X;    // 8.39 MB bf16, live [dt_proj..scan3]; X dead after conv
    float*    hfin  = xpart;           // 16.78 MB, live [scan1..scan3]; xpart dead after gatemul
    float*    outp  = X;               // 33.6 MB (4 partials) spans X+zbuf, live [out_proj..reduce4]

    // 1. convert all GEMM operands to bf16 in one dispatch (x4 vectorized)
    cvt5_kernel<<<(NTOT / 4 + 255) / 256, 256, 0, stream>>>(
        hidden, in_proj, x_proj, dt_proj, out_proj, hb, w_in, w_x, w_dt, w_o);

    // 2. in_proj: xz = hidden @ in_proj^T  (2048 x 4096, K=1024) -> x f32 (X) / z f32
    gemm_bf<3><<<dim3(MROWS / 128, (2 * DINNER) / 128, 1), 256, 0, stream>>>(
        hb, w_in, X, zbuf, nullptr, MROWS, 2 * DINNER, DMODEL);

    // 3. conv+silu -> xc bf16 (over dead w_in)  ++  text gate (fused)
    convgate_kernel<<<CONVBLK + BATCH * GDIM, 256, 0, stream>>>(
        X, conv_w, conv_b, xc, x_text, gate_w, gate_b, gate);

    // 4. x_proj: x_dbl = xc @ x_proj^T (2048 x 96, K=2048), split-K=32 -> partials (xpart)
    gemm_bf<0><<<dim3(MROWS / 128, 1, SPLITX), 256, 0, stream>>>(
        xc, w_x, xpart, nullptr, nullptr, MROWS, GDIM, DINNER);

    // 5. reduce partials + gate -> dt bf16, Bm, Cm
    gatemul_kernel<<<(MROWS * GDIM + 255) / 256, 256, 0, stream>>>(
        xpart, gate, dt, Bm, Cm);

    // 6. dt_proj + softplus: delta bf16 (2048 x 2048, K=64) -> X (dead)
    gemm_bf<1><<<dim3(MROWS / 128, DINNER / 128, 1), 256, 0, stream>>>(
        dt, w_dt, delta, nullptr, dt_bias, MROWS, DINNER, DTRANK);

    // 7. chunked parallel scan, pass 1: per-chunk local h + sum(delta) -> hfin (over dead xpart)
    scan1_kernel<<<dim3(DINNER / 256, BATCH, NCHUNK), 256, 0, stream>>>(
        delta, xc, Bm, A_log, hfin, dsum);

    // 7b. pass 2: exclusive chunk-prefix scan (p rebuilt from dsum), in place over hfin
    scan2_kernel<<<BATCH * DINNER, 256, 0, stream>>>(hfin, dsum, A_log);

    // 8. pass 3: load prefix + replay, y bf16 in place over xc
    scan3_kernel<<<dim3(DINNER / 256, BATCH, NCHUNK), 256, 0, stream>>>(
        delta, xc, zbuf, Bm, Cm, A_log, Dparam, hfin);

    // 9. out_proj (2048 x 1024, K=2048), split-K=4 -> partials over X+zbuf (both dead)
    gemm_bf<0><<<dim3(MROWS / 128, DMODEL / 128, 4), 256, 0, stream>>>(
        xc, w_o, outp, nullptr, nullptr, MROWS, DMODEL, DINNER);

    // 10. reduce partials -> d_out f32
    reduce4_kernel<<<(MROWS * DMODEL + 255) / 256, 256, 0, stream>>>(
        outp, (float*)d_out, MROWS * DMODEL);
}

// Round 5
// 281.510 us; speedup vs baseline: 1.0973x; 1.0238x over previous
//
#include <hip/hip_runtime.h>

// ---------------- Problem constants ----------------
#define BATCH   2
#define SEQLEN  1024
#define DMODEL  1024
#define DINNER  2048
#define DSTATE  16
#define DCONV   4
#define DTRANK  64
#define GDIM    96              // DTRANK + 2*DSTATE
#define MROWS   (BATCH*SEQLEN)  // 2048

#define NCHUNK  64              // chunks over L
#define LCHUNK  16              // SEQLEN / NCHUNK
#define SPLITX  16              // split-K for x_proj
#define SPLITO  2               // split-K for out_proj

typedef __attribute__((ext_vector_type(8))) short bf16x8_t;
typedef __attribute__((ext_vector_type(4))) float f32x4_t;
typedef __attribute__((ext_vector_type(4))) unsigned short u16x4_t;
typedef unsigned short ushort_t;

// bf16 <-> f32 helpers (round-to-nearest-even)
__device__ __forceinline__ unsigned short f2bf(float x) {
    union { float f; unsigned int u; } v; v.f = x;
    unsigned int r = v.u + 0x7FFFu + ((v.u >> 16) & 1u);
    return (unsigned short)(r >> 16);
}
__device__ __forceinline__ float bf2f(unsigned short h) {
    union { unsigned int u; float f; } v; v.u = ((unsigned int)h) << 16;
    return v.f;
}

// async global->LDS, 16B per lane; lds base must be wave-uniform (HW writes lane i at base+16i)
__device__ __forceinline__ void gload_lds16(const ushort_t* g, short* l) {
    __builtin_amdgcn_global_load_lds(
        (const __attribute__((address_space(1))) unsigned int*)g,
        (__attribute__((address_space(3))) unsigned int*)l, 16, 0, 0);
}

// ---------------- fused f32 -> bf16 convert of all GEMM operands (x4 vectorized) ----------------
#define N1 (MROWS*DMODEL)        // hidden
#define N2 (2*DINNER*DMODEL)     // in_proj_w
#define N3 (GDIM*DINNER)         // x_proj_w
#define N4 (DINNER*DTRANK)       // dt_proj_w
#define N5 (DMODEL*DINNER)       // out_proj_w
#define NTOT (N1+N2+N3+N4+N5)
__global__ __launch_bounds__(256)
void cvt5_kernel(const float* __restrict__ s1, const float* __restrict__ s2,
                 const float* __restrict__ s3, const float* __restrict__ s4,
                 const float* __restrict__ s5,
                 ushort_t* o1, ushort_t* o2, ushort_t* o3, ushort_t* o4, ushort_t* o5) {
    int idx = (blockIdx.x * 256 + threadIdx.x) * 4;
    if (idx >= NTOT) return;
    const float* src; ushort_t* dst;
    if (idx < N1)              { src = s1; dst = o1; }
    else if ((idx -= N1) < N2) { src = s2; dst = o2; }
    else if ((idx -= N2) < N3) { src = s3; dst = o3; }
    else if ((idx -= N3) < N4) { src = s4; dst = o4; }
    else                       { idx -= N4; src = s5; dst = o5; }
    f32x4_t v = *(const f32x4_t*)(src + idx);
    u16x4_t o;
    #pragma unroll
    for (int j = 0; j < 4; j++) o[j] = f2bf(v[j]);
    *(u16x4_t*)(dst + idx) = o;
}

// ---------------- 128x128 bf16 NT MFMA GEMM: gload_lds + swizzle + counted-vmcnt pipeline ----
// C[m,n] = sum_k A[m,k]*W[n,k]. A,W bf16 row-major. M%128==0; (K/gridDim.z)%64==0;
// N ragged allowed (B rows clamped; garbage columns masked at write).
// LDS [2 buf][128 rows][32 shorts], linear dest (global_load_lds requirement).
// Swizzle (rule #21, BOTH sides): LDS slot s of row r holds k-chunk s ^ ((r>>1)&3);
// source side pre-permutes lane k-offset; fragment-read slot = quad ^ ((r>>1)&3).
// Bank check: 128B-position (r&1)*4 + (quad^((r>>1)&3)) bijective over r&7 -> 2-way = free.
// Pipeline (T3+T4): per K-step {STAGE(t+1); s_waitcnt vmcnt(4) [counted -- t+1's 4 loads
// stay in flight ACROSS the barrier]; s_barrier; ds_read+MFMA(t); s_barrier}.
// Raw s_barrier via asm (memory clobber = compiler fence); no vmcnt(0) drain except last iter.
// Hazards: barrier1 after counted wait -> tile t visible to all waves; barrier2 after MFMA
// (all ds_reads retired via lgkm before their consuming MFMAs) -> safe to re-stage buffer.
// EPI: 0 = f32 partial -> out0 + blockIdx.z*M*N  (split-K)
//      1 = bf16 softplus(v + bias[n]) -> out0
//      3 = xz split: col < DINNER -> f32 out0; else f32 out1 (both stride DINNER)
template<int EPI>
__global__ __launch_bounds__(256)
void gemm_bf(const ushort_t* __restrict__ A, const ushort_t* __restrict__ W,
             void* __restrict__ out0, void* __restrict__ out1,
             const float* __restrict__ bias, int M, int N, int K) {
    __shared__ __align__(16) short As[2][128 * 32];   // 2 x 8 KB
    __shared__ __align__(16) short Bs[2][128 * 32];   // 2 x 8 KB

    const int tid  = threadIdx.x;
    const int m0   = blockIdx.x * 128;
    const int n0   = blockIdx.y * 128;
    const int klen = K / gridDim.z;
    const int kbeg = blockIdx.z * klen;

    const int w    = tid >> 6;          // wave 0..3
    const int lane = tid & 63;
    const int quad = lane >> 4;
    const int l15  = lane & 15;
    const int wm   = (w >> 1) * 64;
    const int wn   = (w & 1) * 64;

    // staging: call (w,q) covers LDS rows (2w+q)*16..+15 linearly; lane l -> row +(l>>2), slot l&3.
    const int rA0 = (w * 2 + 0) * 16 + (lane >> 2);
    const int rA1 = (w * 2 + 1) * 16 + (lane >> 2);
    const int kc  = (((lane & 3) ^ ((lane >> 3) & 3)) << 3);   // pre-swizzled global k-offset (shorts)
    const int arow0 = m0 + rA0;
    const int arow1 = m0 + rA1;
    int brow0 = n0 + rA0; if (brow0 > N - 1) brow0 = N - 1;
    int brow1 = n0 + rA1; if (brow1 > N - 1) brow1 = N - 1;

    // fragment-read swizzled slot offset (shorts); loop-invariant
    const int sw = ((quad ^ ((l15 >> 1) & 3)) << 3);

    f32x4_t acc[4][4];
    #pragma unroll
    for (int i = 0; i < 4; i++)
        #pragma unroll
        for (int j = 0; j < 4; j++)
            acc[i][j] = (f32x4_t){0.f, 0.f, 0.f, 0.f};

    // prologue: stage K-step 0 into buf 0 (4 gload_lds per wave)
    {
        const int kk = kbeg + kc;
        gload_lds16(A + (size_t)arow0 * K + kk, &As[0][(w * 2 + 0) * 512]);
        gload_lds16(A + (size_t)arow1 * K + kk, &As[0][(w * 2 + 1) * 512]);
        gload_lds16(W + (size_t)brow0 * K + kk, &Bs[0][(w * 2 + 0) * 512]);
        gload_lds16(W + (size_t)brow1 * K + kk, &Bs[0][(w * 2 + 1) * 512]);
    }

    int cur = 0;
    for (int k0 = 0; k0 < klen; k0 += 32) {
        if (k0 + 32 < klen) {
            // issue next tile's 4 loads; they stay in flight across the barrier
            const int kk = kbeg + k0 + 32 + kc;
            gload_lds16(A + (size_t)arow0 * K + kk, &As[cur ^ 1][(w * 2 + 0) * 512]);
            gload_lds16(A + (size_t)arow1 * K + kk, &As[cur ^ 1][(w * 2 + 1) * 512]);
            gload_lds16(W + (size_t)brow0 * K + kk, &Bs[cur ^ 1][(w * 2 + 0) * 512]);
            gload_lds16(W + (size_t)brow1 * K + kk, &Bs[cur ^ 1][(w * 2 + 1) * 512]);
            asm volatile("s_waitcnt vmcnt(4)" ::: "memory");   // drain tile t only
        } else {
            asm volatile("s_waitcnt vmcnt(0)" ::: "memory");   // last tile: full drain
        }
        __builtin_amdgcn_sched_barrier(0);
        asm volatile("s_barrier" ::: "memory");                // barrier1: tile t visible
        __builtin_amdgcn_sched_barrier(0);

        bf16x8_t af[4], bfv[4];
        #pragma unroll
        for (int mi = 0; mi < 4; mi++)
            af[mi] = *(const bf16x8_t*)(&As[cur][(wm + mi * 16 + l15) * 32 + sw]);
        #pragma unroll
        for (int ni = 0; ni < 4; ni++)
            bfv[ni] = *(const bf16x8_t*)(&Bs[cur][(wn + ni * 16 + l15) * 32 + sw]);
        #pragma unroll
        for (int mi = 0; mi < 4; mi++)
            #pragma unroll
            for (int ni = 0; ni < 4; ni++)
                acc[mi][ni] = __builtin_amdgcn_mfma_f32_16x16x32_bf16(af[mi], bfv[ni], acc[mi][ni], 0, 0, 0);

        __builtin_amdgcn_sched_barrier(0);
        asm volatile("s_barrier" ::: "memory");                // barrier2: reads retired
        __builtin_amdgcn_sched_barrier(0);
        cur ^= 1;
    }

    const size_t zoff = (size_t)blockIdx.z * M * N;
    #pragma unroll
    for (int mi = 0; mi < 4; mi++) {
        #pragma unroll
        for (int ni = 0; ni < 4; ni++) {
            #pragma unroll
            for (int r = 0; r < 4; r++) {
                int gm = m0 + wm + mi * 16 + quad * 4 + r;
                int gn = n0 + wn + ni * 16 + l15;
                if (gn < N) {
                    float v = acc[mi][ni][r];
                    if (EPI == 0) {
                        ((float*)out0)[zoff + (size_t)gm * N + gn] = v;
                    } else if (EPI == 1) {
                        float t = v + bias[gn];
                        float sp = (t > 20.f) ? t : log1pf(__expf(t));
                        ((ushort_t*)out0)[(size_t)gm * N + gn] = f2bf(sp);
                    } else {
                        if (gn < DINNER)
                            ((float*)out0)[(size_t)gm * DINNER + gn] = v;
                        else
                            ((float*)out1)[(size_t)gm * DINNER + (gn - DINNER)] = v;
                    }
                }
            }
        }
    }
}

// ---------------- fused: causal conv+silu (blocks [0,CONVBLK)) + text gate ----------------
#define CONVBLK ((MROWS*DINNER)/256)   // 16384
__global__ __launch_bounds__(256)
void convgate_kernel(const float* __restrict__ x,
                     const float* __restrict__ cw,
                     const float* __restrict__ cb,
                     ushort_t* __restrict__ xc,
                     const float* __restrict__ xt,
                     const float* __restrict__ gw,
                     const float* __restrict__ gb,
                     float* __restrict__ gate) {
    if (blockIdx.x < CONVBLK) {
        int idx = blockIdx.x * 256 + threadIdx.x;
        int d  = idx & (DINNER - 1);
        int bl = idx >> 11;
        int l  = bl & (SEQLEN - 1);
        float acc = cb[d];
        #pragma unroll
        for (int j = 0; j < DCONV; j++) {
            int lj = l - (DCONV - 1) + j;
            if (lj >= 0)
                acc += cw[d * DCONV + j] * x[(size_t)(bl - (DCONV - 1) + j) * DINNER + d];
        }
        float v = acc / (1.f + __expf(-acc));   // silu
        xc[idx] = f2bf(v);
    } else {
        int g = blockIdx.x - CONVBLK;
        int b = g / GDIM, j = g % GDIM;
        int tid = threadIdx.x;
        float s = 0.f;
        for (int k = tid; k < DMODEL; k += 256)
            s += xt[b * DMODEL + k] * gw[j * DMODEL + k];
        #pragma unroll
        for (int o = 32; o > 0; o >>= 1) s += __shfl_down(s, o);
        __shared__ float red[4];
        if ((tid & 63) == 0) red[tid >> 6] = s;
        __syncthreads();
        if (tid == 0) {
            float t = red[0] + red[1] + red[2] + red[3] + gb[j];
            gate[b * GDIM + j] = 1.f / (1.f + __expf(-t));
        }
    }
}

// ---------------- reduce SPLITX split-K partials + gate; split into dt bf16, B, C ----------------
__global__ void gatemul_kernel(const float* __restrict__ xp,   // [SPLITX][MROWS][GDIM]
                               const float* __restrict__ gate,
                               ushort_t* __restrict__ dt,
                               float* __restrict__ Bm,
                               float* __restrict__ Cm) {
    int idx = blockIdx.x * 256 + threadIdx.x;
    if (idx >= MROWS * GDIM) return;
    int j  = idx % GDIM;
    int bl = idx / GDIM;
    int b  = bl >> 10;
    float v = 0.f;
    #pragma unroll
    for (int z = 0; z < SPLITX; z++)
        v += xp[(size_t)z * MROWS * GDIM + idx];
    v *= gate[b * GDIM + j];
    if (j < DTRANK)               dt[bl * DTRANK + j] = f2bf(v);
    else if (j < DTRANK + DSTATE) Bm[bl * DSTATE + (j - DTRANK)] = v;
    else                          Cm[bl * DSTATE + (j - DTRANK - DSTATE)] = v;
}

// ---------------- scan pass 1: per-chunk local h and sum(delta) ----------------
// hfin layout: [b][d][c][n] (64B contiguous); dsum layout: [b][c][d] (coalesced write).
// Chunk dA-product p[n] = exp(Ac[n] * sum_s dv_s) -- store only the scalar sum.
__global__ __launch_bounds__(256)
void scan1_kernel(const ushort_t* __restrict__ delta,
                  const ushort_t* __restrict__ xc,
                  const float* __restrict__ Bm,
                  const float* __restrict__ A_log,
                  float* __restrict__ hfin,
                  float* __restrict__ dsum) {
    __shared__ float sBm[LCHUNK][DSTATE];
    int tid = threadIdx.x;
    int d = blockIdx.x * 256 + tid;
    int b = blockIdx.y;
    int c = blockIdx.z;
    int l0 = c * LCHUNK;
    for (int t = tid; t < LCHUNK * DSTATE; t += 256)
        sBm[t >> 4][t & 15] = Bm[((size_t)(b * SEQLEN + l0 + (t >> 4))) * DSTATE + (t & 15)];
    __syncthreads();

    float Ac[DSTATE];
    #pragma unroll
    for (int n = 0; n < DSTATE; n++)
        Ac[n] = -__expf(A_log[d * DSTATE + n]);
    float h[DSTATE];
    #pragma unroll
    for (int n = 0; n < DSTATE; n++) h[n] = 0.f;
    float ds = 0.f;

    for (int s = 0; s < LCHUNK; s++) {
        size_t ix = (size_t)(b * SEQLEN + l0 + s) * DINNER + d;
        float dv = bf2f(delta[ix]);
        float xv = bf2f(xc[ix]);
        float dx = dv * xv;
        ds += dv;
        #pragma unroll
        for (int n = 0; n < DSTATE; n++) {
            float e = __expf(dv * Ac[n]);
            h[n] = h[n] * e + dx * sBm[s][n];
        }
    }
    size_t base = ((size_t)(b * DINNER + d) * NCHUNK + c) * DSTATE;
    #pragma unroll
    for (int n = 0; n < DSTATE; n++) hfin[base + n] = h[n];
    dsum[((size_t)b * NCHUNK + c) * DINNER + d] = ds;
}

// ---------------- scan pass 2: block-parallel exclusive scan over chunks, in place ---------
// One block per (b,d): p[c][n] reconstructed as exp(Ac[n]*dsum[c]); Hillis-Steele over c.
// Overwrites hfin with the EXCLUSIVE prefix (state entering chunk c).
__global__ __launch_bounds__(256)
void scan2_kernel(float* __restrict__ hfin,
                  const float* __restrict__ dsum,
                  const float* __restrict__ A_log) {
    __shared__ float sh[NCHUNK * DSTATE];   // 4 KB
    __shared__ float sp[NCHUNK * DSTATE];   // 4 KB
    __shared__ float sAc[DSTATE];
    __shared__ float sds[NCHUNK];
    const int tid = threadIdx.x;
    const int bd  = blockIdx.x;            // b*DINNER + d
    const int b   = bd >> 11;
    const int d   = bd & (DINNER - 1);
    if (tid < DSTATE) sAc[tid] = -__expf(A_log[d * DSTATE + tid]);
    if (tid < NCHUNK) sds[tid] = dsum[((size_t)b * NCHUNK + tid) * DINNER + d];
    const size_t base = (size_t)bd * (NCHUNK * DSTATE);
    float hl[4];
    #pragma unroll
    for (int r = 0; r < 4; r++) hl[r] = hfin[base + tid + r * 256];
    __syncthreads();
    #pragma unroll
    for (int r = 0; r < 4; r++) {
        int i = tid + r * 256;              // i = c*16 + n
        sh[i] = hl[r];
        sp[i] = __expf(sAc[i & 15] * sds[i >> 4]);
    }
    __syncthreads();
    #pragma unroll
    for (int s = 1; s < NCHUNK; s <<= 1) {
        float nh[4], np[4];
        #pragma unroll
        for (int r = 0; r < 4; r++) {
            int i = tid + r * 256;
            int c = i >> 4;
            if (c >= s) {
                int j = i - (s << 4);
                nh[r] = sh[i] + sp[i] * sh[j];
                np[r] = sp[i] * sp[j];
            } else { nh[r] = sh[i]; np[r] = sp[i]; }
        }
        __syncthreads();
        #pragma unroll
        for (int r = 0; r < 4; r++) { int i = tid + r * 256; sh[i] = nh[r]; sp[i] = np[r]; }
        __syncthreads();
    }
    // exclusive: out[c] = inclusive[c-1]; out[0] = 0
    #pragma unroll
    for (int r = 0; r < 4; r++) {
        int i = tid + r * 256;
        hfin[base + i] = (i >> 4) ? sh[i - 16] : 0.f;
    }
}

// ---------------- scan pass 3: load prefix + replay, emit y bf16 in place over xc ----------
__global__ __launch_bounds__(256)
void scan3_kernel(const ushort_t* __restrict__ delta,
                  ushort_t* __restrict__ xc,     // in: xc, out: y
                  const float* __restrict__ z,
                  const float* __restrict__ Bm,
                  const float* __restrict__ Cm,
                  const float* __restrict__ A_log,
                  const float* __restrict__ Dp,
                  const float* __restrict__ h0) {  // exclusive prefixes from scan2
    __shared__ float sBm[LCHUNK][DSTATE];
    __shared__ float sCm[LCHUNK][DSTATE];
    int tid = threadIdx.x;
    int d = blockIdx.x * 256 + tid;
    int b = blockIdx.y;
    int c = blockIdx.z;
    int l0 = c * LCHUNK;
    for (int t = tid; t < LCHUNK * DSTATE; t += 256) {
        size_t src = ((size_t)(b * SEQLEN + l0 + (t >> 4))) * DSTATE + (t & 15);
        sBm[t >> 4][t & 15] = Bm[src];
        sCm[t >> 4][t & 15] = Cm[src];
    }
    __syncthreads();

    float Ac[DSTATE];
    #pragma unroll
    for (int n = 0; n < DSTATE; n++)
        Ac[n] = -__expf(A_log[d * DSTATE + n]);

    float h[DSTATE];
    size_t hb0 = ((size_t)(b * DINNER + d) * NCHUNK + c) * DSTATE;
    #pragma unroll
    for (int n = 0; n < DSTATE; n++) h[n] = h0[hb0 + n];

    float Dv = Dp[d];

    for (int s = 0; s < LCHUNK; s++) {
        size_t ix = (size_t)(b * SEQLEN + l0 + s) * DINNER + d;
        float dv = bf2f(delta[ix]);
        float xv = bf2f(xc[ix]);
        float dx = dv * xv;
        float y = 0.f;
        #pragma unroll
        for (int n = 0; n < DSTATE; n++) {
            float e = __expf(dv * Ac[n]);
            h[n] = h[n] * e + dx * sBm[s][n];
            y += h[n] * sCm[s][n];
        }
        float zv = z[ix];
        float o = (y + Dv * xv) * (zv / (1.f + __expf(-zv)));
        xc[ix] = f2bf(o);                // same thread read-then-write: safe in place
    }
}

// ---------------- out_proj split-K=2 reduce ----------------
__global__ void reduce2_kernel(const float* __restrict__ p, float* __restrict__ out, int n) {
    int i = blockIdx.x * 256 + threadIdx.x;
    if (i < n)
        out[i] = p[i] + p[(size_t)n + i];
}

// ---------------- launch ----------------
extern "C" void kernel_launch(void* const* d_in, const int* in_sizes, int n_in,
                              void* d_out, int out_size, void* d_ws, size_t ws_size,
                              hipStream_t stream) {
    const float* hidden   = (const float*)d_in[0];
    const float* x_text   = (const float*)d_in[1];
    const float* in_proj  = (const float*)d_in[2];
    const float* conv_w   = (const float*)d_in[3];
    const float* conv_b   = (const float*)d_in[4];
    const float* x_proj   = (const float*)d_in[5];
    const float* dt_proj  = (const float*)d_in[6];
    const float* dt_bias  = (const float*)d_in[7];
    const float* A_log    = (const float*)d_in[8];
    const float* Dparam   = (const float*)d_in[9];
    const float* out_proj = (const float*)d_in[10];
    const float* gate_w   = (const float*)d_in[11];
    const float* gate_b   = (const float*)d_in[12];

    char* ws = (char*)d_ws;
    size_t off = 0;
    auto alloc = [&](size_t bytes) -> char* {
        char* p = ws + off;
        off += (bytes + 255) & ~(size_t)255;
        return p;
    };
    // ~65 MB total.
    ushort_t* hb    = (ushort_t*)alloc((size_t)N1 * 2);   // 4.19 MB
    ushort_t* w_in  = (ushort_t*)alloc((size_t)N2 * 2);   // 8.39 MB -> xc/y after in_proj
    ushort_t* w_x   = (ushort_t*)alloc((size_t)N3 * 2);
    ushort_t* w_dt  = (ushort_t*)alloc((size_t)N4 * 2);
    ushort_t* w_o   = (ushort_t*)alloc((size_t)N5 * 2);   // 4.19 MB
    float*    X     = (float*)alloc((size_t)MROWS * DINNER * 4);  // 16.78 MB
    float*    zbuf  = (float*)alloc((size_t)MROWS * DINNER * 4);  // 16.78 MB
    float*    xpart = (float*)alloc((size_t)SPLITX * MROWS * GDIM * 4);  // 12.58 MB
    float*    hfin2 = (float*)alloc((size_t)BATCH * DINNER * NCHUNK * DSTATE * 4 - (size_t)SPLITX * MROWS * GDIM * 4);  // pad so hfin fits over xpart+
    float*    dsum  = (float*)alloc((size_t)BATCH * NCHUNK * DINNER * 4);  // 1.05 MB
    float*    gate  = (float*)alloc((size_t)BATCH * GDIM * 4);
    float*    Bm    = (float*)alloc((size_t)MROWS * DSTATE * 4);
    float*    Cm    = (float*)alloc((size_t)MROWS * DSTATE * 4);
    ushort_t* dt    = (ushort_t*)alloc((size_t)MROWS * DTRANK * 2);
    (void)hfin2;

    // aliases (lifetimes disjoint, stream-ordered):
    ushort_t* xc    = w_in;            // xc/y bf16, live after in_proj consumed w_in
    ushort_t* delta = (ushort_t*)X;    // 8.39 MB bf16, live [dt_proj..scan3]; X dead after conv
    float*    hfin  = xpart;           // 16.78 MB (spans xpart+hfin2), live [scan1..scan3]
    float*    outp  = X;               // 16.78 MB (2 partials) fits X, live [out_proj..reduce2]

    // 1. convert all GEMM operands to bf16 in one dispatch (x4 vectorized)
    cvt5_kernel<<<(NTOT / 4 + 255) / 256, 256, 0, stream>>>(
        hidden, in_proj, x_proj, dt_proj, out_proj, hb, w_in, w_x, w_dt, w_o);

    // 2. in_proj: xz = hidden @ in_proj^T  (2048 x 4096, K=1024) -> x f32 (X) / z f32
    gemm_bf<3><<<dim3(MROWS / 128, (2 * DINNER) / 128, 1), 256, 0, stream>>>(
        hb, w_in, X, zbuf, nullptr, MROWS, 2 * DINNER, DMODEL);

    // 3. conv+silu -> xc bf16 (over dead w_in)  ++  text gate (fused)
    convgate_kernel<<<CONVBLK + BATCH * GDIM, 256, 0, stream>>>(
        X, conv_w, conv_b, xc, x_text, gate_w, gate_b, gate);

    // 4. x_proj: x_dbl = xc @ x_proj^T (2048 x 96, K=2048), split-K=16 -> partials (xpart)
    gemm_bf<0><<<dim3(MROWS / 128, 1, SPLITX), 256, 0, stream>>>(
        xc, w_x, xpart, nullptr, nullptr, MROWS, GDIM, DINNER);

    // 5. reduce partials + gate -> dt bf16, Bm, Cm
    gatemul_kernel<<<(MROWS * GDIM + 255) / 256, 256, 0, stream>>>(
        xpart, gate, dt, Bm, Cm);

    // 6. dt_proj + softplus: delta bf16 (2048 x 2048, K=64) -> X (dead)
    gemm_bf<1><<<dim3(MROWS / 128, DINNER / 128, 1), 256, 0, stream>>>(
        dt, w_dt, delta, nullptr, dt_bias, MROWS, DINNER, DTRANK);

    // 7. chunked parallel scan, pass 1: per-chunk local h + sum(delta) -> hfin (over dead xpart)
    scan1_kernel<<<dim3(DINNER / 256, BATCH, NCHUNK), 256, 0, stream>>>(
        delta, xc, Bm, A_log, hfin, dsum);

    // 7b. pass 2: exclusive chunk-prefix scan (p rebuilt from dsum), in place over hfin
    scan2_kernel<<<BATCH * DINNER, 256, 0, stream>>>(hfin, dsum, A_log);

    // 8. pass 3: load prefix + replay, y bf16 in place over xc
    scan3_kernel<<<dim3(DINNER / 256, BATCH, NCHUNK), 256, 0, stream>>>(
        delta, xc, zbuf, Bm, Cm, A_log, Dparam, hfin);

    // 9. out_proj (2048 x 1024, K=2048), split-K=2 -> partials over X (delta dead)
    gemm_bf<0><<<dim3(MROWS / 128, DMODEL / 128, SPLITO), 256, 0, stream>>>(
        xc, w_o, outp, nullptr, nullptr, MROWS, DMODEL, DINNER);

    // 10. reduce partials -> d_out f32
    reduce2_kernel<<<(MROWS * DMODEL + 255) / 256, 256, 0, stream>>>(
        outp, (float*)d_out, MROWS * DMODEL);
}